// Round 6
// baseline (283.266 us; speedup 1.0000x reference)
//
#include <hip/hip_runtime.h>
#include <hip/hip_cooperative_groups.h>

namespace cg = cooperative_groups;

// QueryAndGroup: ball query (first 32 idx within radius, index order, padded
// with first hit) + grouped_xyz (xyz[idx]-center) + grouped feature gather.
// Shapes: xyz (8,16384,3) f32, new_xyz (8,1024,3) f32, features (8,64,16384) f32
// Out: (8, 3+64, 1024, 32) f32.
//
// R6: single cooperative kernel. 512 blocks (one per (b,c), exactly 2/CU with
// 64KB LDS) x 512 threads. Phase 1 stages feats[b,c,:] into LDS (independent
// of queries) WHILE running 16 ball queries per block -> query latency hides
// under the 33.5MB staging read. grid.sync(), then phase 2 gathers from LDS
// with fully coalesced float4 writes. Query compaction goes directly to
// global idxq (predicated stores + waitcnt readback) so LDS stays 64KB.

#define BB 8
#define NN 16384
#define SS 1024
#define CC 64
#define NSAMP 32
#define OUTCH (3 + CC)

// float(0.04) to match numpy's weak-scalar promotion (NOT 0.2f*0.2f).
#define R2 0.04f

__global__ __launch_bounds__(512, 4) void fused_kernel(
    const float* __restrict__ xyz,      // (B,N,3)
    const float* __restrict__ new_xyz,  // (B,S,3)
    const float* __restrict__ feats,    // (B,C,N)
    int* __restrict__ idxq,             // ws: (B*S,32)
    float* __restrict__ out)            // (B,67,S,32)
{
    __shared__ float row[NN];           // 64 KB -> exactly 2 blocks/CU

    const int blk  = blockIdx.x;        // 0..511
    const int c    = blk & 63;
    const int b    = blk >> 6;
    const int t    = threadIdx.x;       // 0..511
    const int wave = t >> 6;            // 0..7
    const int lane = t & 63;

    // ---- phase 1a: stage feats[b,c,:] into LDS (coalesced float4) ----
    const float* fr = feats + ((size_t)b * CC + c) * NN;
    #pragma unroll
    for (int i = 0; i < 8; ++i) {
        const int o = (i * 512 + t) * 4;
        *(float4*)(row + o) = *(const float4*)(fr + o);
    }

    // ---- phase 1b: ball queries, 2 per wave (s and s+512, decorrelated) ----
    const float* xb = xyz + (size_t)b * NN * 3;
    const unsigned long long below = (1ull << lane) - 1ull;

    #pragma unroll
    for (int qi = 0; qi < 2; ++qi) {
        const int s = ((blk & 63) << 3) + wave + qi * 512;   // 0..1023
        const int q = (b << 10) + s;
        const float qx = new_xyz[((size_t)b * SS + s) * 3 + 0];
        const float qy = new_xyz[((size_t)b * SS + s) * 3 + 1];
        const float qz = new_xyz[((size_t)b * SS + s) * 3 + 2];

        int count = 0;
        for (int base = 0; base < NN; base += 512) {
            float d2[8];
            #pragma unroll
            for (int j = 0; j < 8; ++j) {
                const int i = base + j * 64 + lane;
                const float dx = qx - xb[i * 3 + 0];
                const float dy = qy - xb[i * 3 + 1];
                const float dz = qz - xb[i * 3 + 2];
                // numpy order, no FMA contraction
                d2[j] = __fadd_rn(__fadd_rn(__fmul_rn(dx, dx),
                                            __fmul_rn(dy, dy)),
                                  __fmul_rn(dz, dz));
            }
            #pragma unroll
            for (int j = 0; j < 8; ++j) {
                const bool within = d2[j] < R2;
                const unsigned long long m = __ballot(within);
                if (within) {
                    const int pos = count + __popcll(m & below);
                    if (pos < NSAMP)
                        idxq[(size_t)q * NSAMP + pos] = base + j * 64 + lane;
                }
                count += __popcll(m);
            }
            if (count >= NSAMP) break;   // wave-uniform
        }

        // drain the predicated compaction stores, then pad + write ch0..2
        __builtin_amdgcn_s_waitcnt(0);
        if (lane < NSAMP) {
            const int cnt = count < NSAMP ? count : NSAMP;
            int idx = 0;
            if (cnt > 0) idx = idxq[(size_t)q * NSAMP + (lane < cnt ? lane : 0)];
            if (lane >= cnt) idxq[(size_t)q * NSAMP + lane] = idx;
            const float gx = xb[idx * 3 + 0] - qx;
            const float gy = xb[idx * 3 + 1] - qy;
            const float gz = xb[idx * 3 + 2] - qz;
            const size_t o = (((size_t)b * OUTCH + 0) * SS + s) * NSAMP + lane;
            out[o + 0 * (size_t)SS * NSAMP] = gx;
            out[o + 1 * (size_t)SS * NSAMP] = gy;
            out[o + 2 * (size_t)SS * NSAMP] = gz;
        }
    }

    __threadfence();            // make idxq visible device-wide (cross-XCD)
    cg::this_grid().sync();

    // ---- phase 2: gather from LDS, coalesced float4 writes ----
    const int k4 = (t & 7) * 4;
    const int s0 = t >> 3;              // 0..63
    const int* ib = idxq + (size_t)b * SS * NSAMP;
    float* ob = out + (((size_t)b * OUTCH + 3 + c) * SS) * NSAMP;
    #pragma unroll
    for (int it = 0; it < 16; ++it) {
        const int s = it * 64 + s0;
        const int4 id = *(const int4*)(ib + (size_t)s * NSAMP + k4);
        float4 v;
        v.x = row[id.x];
        v.y = row[id.y];
        v.z = row[id.z];
        v.w = row[id.w];
        *(float4*)(ob + (size_t)s * NSAMP + k4) = v;
    }
}

// ---------------- fallback path A: R5 two-kernel pipeline ----------------
__global__ __launch_bounds__(256) void query_kernel(
    const float* __restrict__ xyz, const float* __restrict__ new_xyz,
    int* __restrict__ idxq, float* __restrict__ out)
{
    __shared__ int sidx[4][NSAMP];

    const int t    = threadIdx.x;
    const int wave = t >> 6;
    const int lane = t & 63;
    const int q    = blockIdx.x * 4 + wave;
    const int b    = q >> 10;
    const int s    = q & (SS - 1);

    const float* xb = xyz + (size_t)b * NN * 3;
    const float qx = new_xyz[((size_t)b * SS + s) * 3 + 0];
    const float qy = new_xyz[((size_t)b * SS + s) * 3 + 1];
    const float qz = new_xyz[((size_t)b * SS + s) * 3 + 2];
    const unsigned long long below = (1ull << lane) - 1ull;

    int count = 0;
    for (int base = 0; base < NN; base += 512) {
        float d2[8];
        #pragma unroll
        for (int j = 0; j < 8; ++j) {
            const int i = base + j * 64 + lane;
            const float dx = qx - xb[i * 3 + 0];
            const float dy = qy - xb[i * 3 + 1];
            const float dz = qz - xb[i * 3 + 2];
            d2[j] = __fadd_rn(__fadd_rn(__fmul_rn(dx, dx),
                                        __fmul_rn(dy, dy)),
                              __fmul_rn(dz, dz));
        }
        #pragma unroll
        for (int j = 0; j < 8; ++j) {
            const bool within = d2[j] < R2;
            const unsigned long long m = __ballot(within);
            if (within) {
                const int pos = count + __popcll(m & below);
                if (pos < NSAMP) sidx[wave][pos] = base + j * 64 + lane;
            }
            count += __popcll(m);
        }
        if (count >= NSAMP) break;
    }
    __syncthreads();
    const int cnt = count < NSAMP ? count : NSAMP;
    const int first = (cnt > 0) ? sidx[wave][0] : 0;
    if (lane < NSAMP && lane >= cnt) sidx[wave][lane] = first;
    __syncthreads();

    if (lane < NSAMP) {
        const int idx = sidx[wave][lane];
        idxq[(size_t)q * NSAMP + lane] = idx;
        const float gx = xb[idx * 3 + 0] - qx;
        const float gy = xb[idx * 3 + 1] - qy;
        const float gz = xb[idx * 3 + 2] - qz;
        const size_t o = (((size_t)b * OUTCH + 0) * SS + s) * NSAMP + lane;
        out[o + 0 * (size_t)SS * NSAMP] = gx;
        out[o + 1 * (size_t)SS * NSAMP] = gy;
        out[o + 2 * (size_t)SS * NSAMP] = gz;
    }
}

__global__ __launch_bounds__(512) void gather_kernel(
    const float* __restrict__ feats, const int* __restrict__ idxq,
    float* __restrict__ out)
{
    __shared__ float row[NN];

    const int c = blockIdx.x;
    const int b = blockIdx.y;
    const int t = threadIdx.x;

    const float* fr = feats + ((size_t)b * CC + c) * NN;
    #pragma unroll
    for (int i = 0; i < 8; ++i) {
        const int o = (i * 512 + t) * 4;
        *(float4*)(row + o) = *(const float4*)(fr + o);
    }
    __syncthreads();

    const int k4 = (t & 7) * 4;
    const int s0 = t >> 3;
    const int* ib = idxq + (size_t)b * SS * NSAMP;
    float* ob = out + (((size_t)b * OUTCH + 3 + c) * SS) * NSAMP;
    #pragma unroll
    for (int it = 0; it < 16; ++it) {
        const int s = it * 64 + s0;
        const int4 id = *(const int4*)(ib + (size_t)s * NSAMP + k4);
        float4 v;
        v.x = row[id.x];
        v.y = row[id.y];
        v.z = row[id.z];
        v.w = row[id.w];
        *(float4*)(ob + (size_t)s * NSAMP + k4) = v;
    }
}

// ---------------- fallback path B: fully fused single-wave (tiny ws) --------
__global__ __launch_bounds__(64) void qg_fused(
    const float* __restrict__ xyz, const float* __restrict__ new_xyz,
    const float* __restrict__ feats, float* __restrict__ out)
{
    const int bs   = blockIdx.x;
    const int b    = bs >> 10;
    const int s    = bs & (SS - 1);
    const int lane = threadIdx.x;

    const float* xb = xyz + (size_t)b * NN * 3;
    const float qx = new_xyz[((size_t)b * SS + s) * 3 + 0];
    const float qy = new_xyz[((size_t)b * SS + s) * 3 + 1];
    const float qz = new_xyz[((size_t)b * SS + s) * 3 + 2];

    __shared__ int sidx[NSAMP];
    int count = 0;
    for (int base = 0; base < NN; base += 64) {
        const int i = base + lane;
        const float dx = qx - xb[i * 3 + 0];
        const float dy = qy - xb[i * 3 + 1];
        const float dz = qz - xb[i * 3 + 2];
        const float d2 = __fadd_rn(__fadd_rn(__fmul_rn(dx, dx),
                                             __fmul_rn(dy, dy)),
                                   __fmul_rn(dz, dz));
        const bool within = d2 < R2;
        const unsigned long long m = __ballot(within);
        if (within) {
            const int pos = count + __popcll(m & ((1ull << lane) - 1ull));
            if (pos < NSAMP) sidx[pos] = i;
        }
        count += __popcll(m);
        if (count >= NSAMP) break;
    }
    __syncthreads();
    const int cnt = count < NSAMP ? count : NSAMP;
    const int first = (cnt > 0) ? sidx[0] : 0;
    if (lane < NSAMP && lane >= cnt) sidx[lane] = first;
    __syncthreads();

    const int k    = lane & 31;
    const int half = lane >> 5;
    const int idx  = sidx[k];
    const size_t obase = (((size_t)b * OUTCH + 0) * SS + s) * NSAMP + k;
    if (half == 0) {
        out[obase + 0 * (size_t)SS * NSAMP] = xb[idx * 3 + 0] - qx;
        out[obase + 1 * (size_t)SS * NSAMP] = xb[idx * 3 + 1] - qy;
        out[obase + 2 * (size_t)SS * NSAMP] = xb[idx * 3 + 2] - qz;
    }
    const float* fb = feats + (size_t)b * CC * NN;
    const size_t fo = (((size_t)b * OUTCH + 3) * SS + s) * NSAMP + k;
    for (int cch = half; cch < CC; cch += 2) {
        out[fo + (size_t)cch * SS * NSAMP] = fb[(size_t)cch * NN + idx];
    }
}

extern "C" void kernel_launch(void* const* d_in, const int* in_sizes, int n_in,
                              void* d_out, int out_size, void* d_ws, size_t ws_size,
                              hipStream_t stream) {
    const float* xyz     = (const float*)d_in[0];
    const float* new_xyz = (const float*)d_in[1];
    const float* feats   = (const float*)d_in[2];
    float* out           = (float*)d_out;

    const size_t idx_bytes = (size_t)BB * SS * NSAMP * sizeof(int);     // 1 MB

    if (ws_size >= idx_bytes) {
        int* idxq = (int*)d_ws;
        void* args[] = {(void*)&xyz, (void*)&new_xyz, (void*)&feats,
                        (void*)&idxq, (void*)&out};
        hipError_t err = hipLaunchCooperativeKernel(
            (const void*)fused_kernel, dim3(512), dim3(512), args, 0, stream);
        if (err != hipSuccess) {
            (void)hipGetLastError();   // clear, fall back to two-kernel path
            query_kernel<<<2048, 256, 0, stream>>>(xyz, new_xyz, idxq, out);
            gather_kernel<<<dim3(CC, BB), 512, 0, stream>>>(feats, idxq, out);
        }
    } else {
        qg_fused<<<BB * SS, 64, 0, stream>>>(xyz, new_xyz, feats, out);
    }
}

// Round 7
// 118.571 us; speedup vs baseline: 2.3890x; 2.3890x over previous
//
#include <hip/hip_runtime.h>

// QueryAndGroup: ball query (first 32 idx within radius, index order, padded
// with first hit) + grouped_xyz (xyz[idx]-center) + grouped feature gather.
// Shapes: xyz (8,16384,3) f32, new_xyz (8,1024,3) f32, features (8,64,16384) f32
// Out: (8, 3+64, 1024, 32) f32.
//
// R7: back to the R5 two-kernel structure (R6's cooperative grid.sync cost
// ~160us on gfx950 — per-block L2 flush across 8 non-coherent XCDs; never
// again). Changes vs R5:
//  (a) gather preloads all 16 int4 idxq rows into regs BEFORE __syncthreads,
//      hiding their L2 latency under the in-flight feats staging loads;
//  (b) query scans in 1024-pt chunks (48 loads per latency window) to halve
//      the serial-latency count for full-scan corner stragglers.
// Traffic: feats 33.5MB read (partly L3-hit) + out 70MB write + idx 2MB.

#define BB 8
#define NN 16384
#define SS 1024
#define CC 64
#define NSAMP 32
#define OUTCH (3 + CC)

// float(0.04) to match numpy's weak-scalar promotion (NOT 0.2f*0.2f).
#define R2 0.04f

// ---------------- kernel A: ball query ----------------
// 4 waves/block, one query per wave, 1024-pt chunks (all 48 loads batched
// ahead of the ballot phase -> one memory latency per 1024 points).
__global__ __launch_bounds__(256) void query_kernel(
    const float* __restrict__ xyz,      // (B,N,3)
    const float* __restrict__ new_xyz,  // (B,S,3)
    int* __restrict__ idxq,             // ws: (B*S,32)
    float* __restrict__ out)            // (B,67,S,32)
{
    __shared__ int sidx[4][NSAMP];

    const int t    = threadIdx.x;
    const int wave = t >> 6;
    const int lane = t & 63;
    const int q    = blockIdx.x * 4 + wave;   // 0..8191
    const int b    = q >> 10;
    const int s    = q & (SS - 1);

    const float* xb = xyz + (size_t)b * NN * 3;
    const float qx = new_xyz[((size_t)b * SS + s) * 3 + 0];
    const float qy = new_xyz[((size_t)b * SS + s) * 3 + 1];
    const float qz = new_xyz[((size_t)b * SS + s) * 3 + 2];
    const unsigned long long below = (1ull << lane) - 1ull;

    int count = 0;
    for (int base = 0; base < NN; base += 1024) {
        float d2[16];
        #pragma unroll
        for (int j = 0; j < 16; ++j) {
            const int i = base + j * 64 + lane;
            const float dx = qx - xb[i * 3 + 0];
            const float dy = qy - xb[i * 3 + 1];
            const float dz = qz - xb[i * 3 + 2];
            // numpy order, no FMA contraction
            d2[j] = __fadd_rn(__fadd_rn(__fmul_rn(dx, dx),
                                        __fmul_rn(dy, dy)),
                              __fmul_rn(dz, dz));
        }
        #pragma unroll
        for (int j = 0; j < 16; ++j) {
            const bool within = d2[j] < R2;
            const unsigned long long m = __ballot(within);
            if (within) {
                const int pos = count + __popcll(m & below);
                if (pos < NSAMP) sidx[wave][pos] = base + j * 64 + lane;
            }
            count += __popcll(m);
        }
        if (count >= NSAMP) break;   // wave-uniform
    }
    __syncthreads();
    const int cnt = count < NSAMP ? count : NSAMP;
    const int first = (cnt > 0) ? sidx[wave][0] : 0;
    if (lane < NSAMP && lane >= cnt) sidx[wave][lane] = first;
    __syncthreads();

    if (lane < NSAMP) {
        const int idx = sidx[wave][lane];
        idxq[(size_t)q * NSAMP + lane] = idx;
        // grouped_xyz -> out channels 0..2 (128B coalesced per channel)
        const float gx = xb[idx * 3 + 0] - qx;
        const float gy = xb[idx * 3 + 1] - qy;
        const float gz = xb[idx * 3 + 2] - qz;
        const size_t o = (((size_t)b * OUTCH + 0) * SS + s) * NSAMP + lane;
        out[o + 0 * (size_t)SS * NSAMP] = gx;
        out[o + 1 * (size_t)SS * NSAMP] = gy;
        out[o + 2 * (size_t)SS * NSAMP] = gz;
    }
}

// ---------------- kernel B: row-in-LDS gather ----------------
// one block per (b,c): stage feats[b,c,:] (64KB) in LDS, preload idxq rows
// into regs while the staging loads are in flight, then gather via LDS and
// write out[b,3+c,:,:] fully coalesced (8KB contiguous per iteration).
__global__ __launch_bounds__(512) void gather_kernel(
    const float* __restrict__ feats,    // (B,C,N)
    const int*   __restrict__ idxq,     // (B*S,32)
    float* __restrict__ out)            // (B,67,S,32)
{
    __shared__ float row[NN];           // 64 KB -> 2 blocks/CU

    const int c = blockIdx.x;           // 0..63
    const int b = blockIdx.y;           // 0..7
    const int t = threadIdx.x;          // 0..511

    // stage the full channel row, coalesced float4 (8 KB per wave-instr)
    const float* fr = feats + ((size_t)b * CC + c) * NN;
    #pragma unroll
    for (int i = 0; i < 8; ++i) {
        const int o = (i * 512 + t) * 4;
        *(float4*)(row + o) = *(const float4*)(fr + o);
    }

    // preload all idxq rows this thread needs (L2 latency hides under the
    // staging loads still in flight)
    const int k4 = (t & 7) * 4;
    const int s0 = t >> 3;              // 0..63
    const int* ib = idxq + (size_t)b * SS * NSAMP;
    int4 id[16];
    #pragma unroll
    for (int it = 0; it < 16; ++it) {
        const int s = it * 64 + s0;
        id[it] = *(const int4*)(ib + (size_t)s * NSAMP + k4);
    }
    __syncthreads();

    // gather + write: per iter, 512 threads cover 64 s x 32 k (8KB contig)
    float* ob = out + (((size_t)b * OUTCH + 3 + c) * SS) * NSAMP;
    #pragma unroll
    for (int it = 0; it < 16; ++it) {
        const int s = it * 64 + s0;
        float4 v;
        v.x = row[id[it].x];
        v.y = row[id[it].y];
        v.z = row[id[it].z];
        v.w = row[id[it].w];
        *(float4*)(ob + (size_t)s * NSAMP + k4) = v;
    }
}

// ---------------- fallback: R1 fused kernel (if ws too small) ----------------
__global__ __launch_bounds__(64) void qg_fused(
    const float* __restrict__ xyz, const float* __restrict__ new_xyz,
    const float* __restrict__ feats, float* __restrict__ out)
{
    const int bs   = blockIdx.x;
    const int b    = bs >> 10;
    const int s    = bs & (SS - 1);
    const int lane = threadIdx.x;

    const float* xb = xyz + (size_t)b * NN * 3;
    const float qx = new_xyz[((size_t)b * SS + s) * 3 + 0];
    const float qy = new_xyz[((size_t)b * SS + s) * 3 + 1];
    const float qz = new_xyz[((size_t)b * SS + s) * 3 + 2];

    __shared__ int sidx[NSAMP];
    int count = 0;
    for (int base = 0; base < NN; base += 64) {
        const int i = base + lane;
        const float dx = qx - xb[i * 3 + 0];
        const float dy = qy - xb[i * 3 + 1];
        const float dz = qz - xb[i * 3 + 2];
        const float d2 = __fadd_rn(__fadd_rn(__fmul_rn(dx, dx),
                                             __fmul_rn(dy, dy)),
                                   __fmul_rn(dz, dz));
        const bool within = d2 < R2;
        const unsigned long long m = __ballot(within);
        if (within) {
            const int pos = count + __popcll(m & ((1ull << lane) - 1ull));
            if (pos < NSAMP) sidx[pos] = i;
        }
        count += __popcll(m);
        if (count >= NSAMP) break;
    }
    __syncthreads();
    const int cnt = count < NSAMP ? count : NSAMP;
    const int first = (cnt > 0) ? sidx[0] : 0;
    if (lane < NSAMP && lane >= cnt) sidx[lane] = first;
    __syncthreads();

    const int k    = lane & 31;
    const int half = lane >> 5;
    const int idx  = sidx[k];
    const size_t obase = (((size_t)b * OUTCH + 0) * SS + s) * NSAMP + k;
    if (half == 0) {
        out[obase + 0 * (size_t)SS * NSAMP] = xb[idx * 3 + 0] - qx;
        out[obase + 1 * (size_t)SS * NSAMP] = xb[idx * 3 + 1] - qy;
        out[obase + 2 * (size_t)SS * NSAMP] = xb[idx * 3 + 2] - qz;
    }
    const float* fb = feats + (size_t)b * CC * NN;
    const size_t fo = (((size_t)b * OUTCH + 3) * SS + s) * NSAMP + k;
    for (int cch = half; cch < CC; cch += 2) {
        out[fo + (size_t)cch * SS * NSAMP] = fb[(size_t)cch * NN + idx];
    }
}

extern "C" void kernel_launch(void* const* d_in, const int* in_sizes, int n_in,
                              void* d_out, int out_size, void* d_ws, size_t ws_size,
                              hipStream_t stream) {
    const float* xyz     = (const float*)d_in[0];
    const float* new_xyz = (const float*)d_in[1];
    const float* feats   = (const float*)d_in[2];
    float* out           = (float*)d_out;

    const size_t idx_bytes = (size_t)BB * SS * NSAMP * sizeof(int);     // 1 MB

    if (ws_size >= idx_bytes) {
        int* idxq = (int*)d_ws;
        query_kernel<<<2048, 256, 0, stream>>>(xyz, new_xyz, idxq, out);
        gather_kernel<<<dim3(CC, BB), 512, 0, stream>>>(feats, idxq, out);
    } else {
        qg_fused<<<BB * SS, 64, 0, stream>>>(xyz, new_xyz, feats, out);
    }
}